// Round 3
// baseline (5006.133 us; speedup 1.0000x reference)
//
#include <hip/hip_runtime.h>

#define NPTS 65536

__device__ __forceinline__ float relu(float v) { return v > 0.f ? v : 0.f; }

// ============ k1a: h1T[c][p] = relu(x @ W1.T + b1), no per-thread arrays
__global__ __launch_bounds__(256, 4) void k1a(
    const float* __restrict__ x, const float* __restrict__ W1, const float* __restrict__ b1,
    float* __restrict__ h1T) {
  int p = blockIdx.x * 256 + threadIdx.x;
  float x0 = x[p * 3 + 0], x1 = x[p * 3 + 1], x2 = x[p * 3 + 2];
#pragma unroll
  for (int c = 0; c < 64; ++c) {
    float v = relu(fmaf(W1[c * 3 + 0], x0, fmaf(W1[c * 3 + 1], x1, fmaf(W1[c * 3 + 2], x2, b1[c]))));
    h1T[(size_t)c * NPTS + p] = v;
  }
}

// ============ generic LDS-tiled GEMM: out[n][p] = act(A[k][p] . W[n][k] + bias[n])
// Block: 64 points x 64 channels, 4 waves; lane = point; wave w owns 16 channels.
// Weights wave-uniform -> s_load. acc[2][8] = 16 VGPRs (no spill).
template <int K, int KC, bool MAXPOOL>
__global__ __launch_bounds__(256, 4) void gemmT(
    const float* __restrict__ A, const float* __restrict__ W, int SW,
    const float* __restrict__ bias, float* __restrict__ out) {
  __shared__ float sA[KC][64];
  int tid = threadIdx.x;
  int lane = tid & 63;
  int w = __builtin_amdgcn_readfirstlane(tid >> 6);
  int p0 = blockIdx.x * 64;
  int cb = blockIdx.y * 64 + w * 16;

  float acc[2][8];
#pragma unroll
  for (int cg = 0; cg < 2; ++cg)
#pragma unroll
    for (int cc = 0; cc < 8; ++cc) acc[cg][cc] = bias[cb + cg * 8 + cc];

  for (int kc0 = 0; kc0 < K; kc0 += KC) {
    if (kc0) __syncthreads();
    // stage A chunk [KC][64], coalesced float4 reads, conflict-free b128 writes
#pragma unroll
    for (int it = 0; it < KC / 16; ++it) {
      int f = tid + it * 256;            // float4 index in the KC*64 tile
      int row = f >> 4, c4 = (f & 15) * 4;
      *(float4*)&sA[row][c4] = *(const float4*)(A + (size_t)(kc0 + row) * NPTS + p0 + c4);
    }
    __syncthreads();
#pragma unroll
    for (int k = 0; k < KC; ++k) {
      float av = sA[k][lane];
#pragma unroll
      for (int cg = 0; cg < 2; ++cg)
#pragma unroll
        for (int cc = 0; cc < 8; ++cc)
          acc[cg][cc] = fmaf(av, W[(size_t)(cb + cg * 8 + cc) * SW + kc0 + k], acc[cg][cc]);
    }
  }

  if (MAXPOOL) {
    // fused column-max: reduce over the 64 points of this block, lane0 writes gpart
#pragma unroll
    for (int cg = 0; cg < 2; ++cg)
#pragma unroll
      for (int cc = 0; cc < 8; ++cc) {
        float v = relu(acc[cg][cc]);
#pragma unroll
        for (int off = 32; off >= 1; off >>= 1) v = fmaxf(v, __shfl_xor(v, off));
        if (lane == 0) out[(size_t)blockIdx.x * 1024 + cb + cg * 8 + cc] = v;
      }
  } else {
#pragma unroll
    for (int cg = 0; cg < 2; ++cg)
#pragma unroll
      for (int cc = 0; cc < 8; ++cc)
        out[(size_t)(cb + cg * 8 + cc) * NPTS + p0 + lane] = relu(acc[cg][cc]);
  }
}

// ============ kgmax: g[c] = max over 1024 point-block rows of gpart[1024][1024]
__global__ __launch_bounds__(256) void kgmax(const float* __restrict__ gpart, float* __restrict__ g) {
  int t = blockIdx.x * 256 + threadIdx.x;  // 16384 threads
  int c = t & 1023, rg = t >> 10;
  const float* gp = gpart + (size_t)rg * 64 * 1024 + c;
  float m = 0.f;
#pragma unroll 8
  for (int r = 0; r < 64; ++r) m = fmaxf(m, gp[(size_t)r * 1024]);
  atomicMax((unsigned int*)(g + c), __float_as_uint(m));  // all values >= 0
}

// ============ kc5: c5[c] = W5[c][64:1088] @ g + b5[c]
__global__ __launch_bounds__(256) void kc5(
    const float* __restrict__ W5, const float* __restrict__ b5,
    const float* __restrict__ g, float* __restrict__ c5) {
  int tid = threadIdx.x;
  int ci = tid >> 3, kg = tid & 7;
  int c = blockIdx.x * 32 + ci;
  const float* wrow = W5 + (size_t)c * 1088 + 64 + kg * 128;
  const float* gp = g + kg * 128;
  float acc = 0.f;
#pragma unroll 8
  for (int k = 0; k < 128; ++k) acc += wrow[k] * gp[k];
#pragma unroll
  for (int off = 1; off <= 4; off <<= 1) acc += __shfl_xor(acc, off);
  if (kg == 0) c5[c] = acc + b5[c];
}

// ============ kL8: out[p] = z7[p] @ W8 + b8   K=128 split over 4 waves (32 each), 64 pts/block
__global__ __launch_bounds__(256) void kL8(
    const float* __restrict__ z7T, const float* __restrict__ W8, const float* __restrict__ b8,
    float* __restrict__ out) {
  __shared__ float part[4][64];
  int tid = threadIdx.x;
  int lane = tid & 63;
  int w = __builtin_amdgcn_readfirstlane(tid >> 6);
  int p = blockIdx.x * 64 + lane;
  float acc = 0.f;
#pragma unroll
  for (int j = 0; j < 32; ++j)
    acc = fmaf(z7T[(size_t)(w * 32 + j) * NPTS + p], W8[w * 32 + j], acc);
  part[w][lane] = acc;
  __syncthreads();
  if (tid < 64)
    out[blockIdx.x * 64 + tid] =
        part[0][tid] + part[1][tid] + part[2][tid] + part[3][tid] + b8[0];
}

extern "C" void kernel_launch(void* const* d_in, const int* in_sizes, int n_in,
                              void* d_out, int out_size, void* d_ws, size_t ws_size,
                              hipStream_t stream) {
  const float* x  = (const float*)d_in[0];
  const float* W1 = (const float*)d_in[1];  const float* b1 = (const float*)d_in[2];
  const float* W2 = (const float*)d_in[3];  const float* b2 = (const float*)d_in[4];
  const float* W3 = (const float*)d_in[5];  const float* b3 = (const float*)d_in[6];
  const float* W4 = (const float*)d_in[7];  const float* b4 = (const float*)d_in[8];
  const float* W5 = (const float*)d_in[9];  const float* b5 = (const float*)d_in[10];
  const float* W6 = (const float*)d_in[11]; const float* b6 = (const float*)d_in[12];
  const float* W7 = (const float*)d_in[13]; const float* b7 = (const float*)d_in[14];
  const float* W8 = (const float*)d_in[15]; const float* b8 = (const float*)d_in[16];
  float* out = (float*)d_out;

  // Workspace overlays (lifetimes):
  //   z5T  [0,128M)    kL5->kL6        z7T [0,32M)    kL7->kL8 (z5T dead)
  //   h2T  [128M,144M)  L2 ->kL5
  //   h1T  [144M,160M)  k1a->L2
  //   y3T  [144M,176M)  L3 ->L4  (over dead h1T)
  //   gpart[176M,180M)  L4 ->kgmax
  //   z6T  [144M,208M)  L6 ->L7  (over dead y3T+gpart)
  //   g [208M,+4K)  c5 [208M+4K,+2K)
  char* ws = (char*)d_ws;
  float* z5T   = (float*)(ws);
  float* z7T   = (float*)(ws);
  float* h2T   = (float*)(ws + 134217728ULL);
  float* h1T   = (float*)(ws + 150994944ULL);
  float* y3T   = (float*)(ws + 150994944ULL);
  float* gpart = (float*)(ws + 184549376ULL);
  float* z6T   = (float*)(ws + 150994944ULL);
  float* g     = (float*)(ws + 218103808ULL);
  float* c5    = (float*)(ws + 218103808ULL + 4096);

  hipMemsetAsync(g, 0, 1024 * sizeof(float), stream);  // max identity (relu outputs >= 0)

  k1a<<<256, 256, 0, stream>>>(x, W1, b1, h1T);
  gemmT<64, 64, false><<<dim3(1024, 1), 256, 0, stream>>>(h1T, W2, 64, b2, h2T);    // L2
  gemmT<64, 64, false><<<dim3(1024, 2), 256, 0, stream>>>(h2T, W3, 64, b3, y3T);    // L3
  gemmT<128, 128, true><<<dim3(1024, 16), 256, 0, stream>>>(y3T, W4, 128, b4, gpart); // L4+max
  kgmax<<<64, 256, 0, stream>>>(gpart, g);
  kc5<<<16, 256, 0, stream>>>(W5, b5, g, c5);
  gemmT<64, 64, false><<<dim3(1024, 8), 256, 0, stream>>>(h2T, W5, 1088, c5, z5T);  // L5 (cols :64)
  gemmT<512, 128, false><<<dim3(1024, 4), 256, 0, stream>>>(z5T, W6, 512, b6, z6T); // L6
  gemmT<256, 128, false><<<dim3(1024, 2), 256, 0, stream>>>(z6T, W7, 256, b7, z7T); // L7
  kL8<<<1024, 256, 0, stream>>>(z7T, W8, b8, out);
}

// Round 4
// 659.101 us; speedup vs baseline: 7.5954x; 7.5954x over previous
//
#include <hip/hip_runtime.h>

#define NPTS 65536

__device__ __forceinline__ float relu(float v) { return v > 0.f ? v : 0.f; }

// ============ k1a: h1T[c][p] = relu(x @ W1.T + b1)
__global__ __launch_bounds__(256, 4) void k1a(
    const float* __restrict__ x, const float* __restrict__ W1, const float* __restrict__ b1,
    float* __restrict__ h1T) {
  int p = blockIdx.x * 256 + threadIdx.x;
  float x0 = x[p * 3 + 0], x1 = x[p * 3 + 1], x2 = x[p * 3 + 2];
#pragma unroll
  for (int c = 0; c < 64; ++c) {
    float v = relu(fmaf(W1[c * 3 + 0], x0, fmaf(W1[c * 3 + 1], x1, fmaf(W1[c * 3 + 2], x2, b1[c]))));
    h1T[(size_t)c * NPTS + p] = v;
  }
}

// ============ gemm2: out[c][p] = relu(sum_k W[c][k]*A[k][p] + bias[c])
// Double LDS tile (A and W), 8pt x 8ch register micro-tile per thread.
// PT x CT block tile, 256 threads. MAXPOOL: fused per-block point-max -> out[bx*1024+c].
template <int PT, int CT, bool MAXPOOL>
__global__ __launch_bounds__(256, 3) void gemm2(
    const float* __restrict__ A, const float* __restrict__ W, int SW, int K,
    const float* __restrict__ bias, float* __restrict__ out) {
  constexpr int KC = 16;
  constexpr int PTP = PT + 4, CTP = CT + 4;
  constexpr int NPG = PT / 8;          // point-groups (16 or 32)
  __shared__ float sA[KC][PTP];
  __shared__ float sW[KC][CTP];
  __shared__ float sred[CT];
  int tid = threadIdx.x;
  int ptg = tid & (NPG - 1);
  int chg = tid / NPG;
  int p0 = blockIdx.x * PT;
  int cb = blockIdx.y * CT;

  float acc[8][8];
#pragma unroll
  for (int j = 0; j < 8; ++j) {
    float bv = bias[cb + chg * 8 + j];
#pragma unroll
    for (int i = 0; i < 8; ++i) acc[i][j] = bv;
  }

  for (int kc0 = 0; kc0 < K; kc0 += KC) {
    if (kc0) __syncthreads();
    // stage A chunk [KC][PT]: coalesced float4 global reads
#pragma unroll
    for (int it = 0; it < (KC * PT / 4) / 256; ++it) {
      int f = tid + it * 256;
      int row = f / (PT / 4), c4 = (f % (PT / 4)) * 4;
      *(float4*)&sA[row][c4] = *(const float4*)(A + (size_t)(kc0 + row) * NPTS + p0 + c4);
    }
    // stage W chunk transposed -> sW[k][c]
#pragma unroll
    for (int it = 0; it < (KC * CT / 4) / 256; ++it) {
      int f = tid + it * 256;
      int c = f >> 2, kq = (f & 3) * 4;
      float4 wv = *(const float4*)(W + (size_t)(cb + c) * SW + kc0 + kq);
      sW[kq + 0][c] = wv.x; sW[kq + 1][c] = wv.y; sW[kq + 2][c] = wv.z; sW[kq + 3][c] = wv.w;
    }
    __syncthreads();
#pragma unroll
    for (int k = 0; k < KC; ++k) {
      float4 a0 = *(float4*)&sA[k][ptg * 8];
      float4 a1 = *(float4*)&sA[k][ptg * 8 + 4];
      float4 w0 = *(float4*)&sW[k][chg * 8];
      float4 w1 = *(float4*)&sW[k][chg * 8 + 4];
      float av[8] = {a0.x, a0.y, a0.z, a0.w, a1.x, a1.y, a1.z, a1.w};
      float wv[8] = {w0.x, w0.y, w0.z, w0.w, w1.x, w1.y, w1.z, w1.w};
#pragma unroll
      for (int i = 0; i < 8; ++i)
#pragma unroll
        for (int j = 0; j < 8; ++j)
          acc[i][j] = fmaf(av[i], wv[j], acc[i][j]);
    }
  }

  if (!MAXPOOL) {
#pragma unroll
    for (int j = 0; j < 8; ++j) {
      size_t rowoff = (size_t)(cb + chg * 8 + j) * NPTS + p0 + ptg * 8;
      *(float4*)(out + rowoff) =
          make_float4(relu(acc[0][j]), relu(acc[1][j]), relu(acc[2][j]), relu(acc[3][j]));
      *(float4*)(out + rowoff + 4) =
          make_float4(relu(acc[4][j]), relu(acc[5][j]), relu(acc[6][j]), relu(acc[7][j]));
    }
  } else {
    // fused max over this block's PT points (relu applied first)
#pragma unroll
    for (int j = 0; j < 8; ++j) {
      float m = relu(acc[0][j]);
#pragma unroll
      for (int i = 1; i < 8; ++i) m = fmaxf(m, relu(acc[i][j]));
#pragma unroll
      for (int off = 1; off < NPG && off < 64; off <<= 1) m = fmaxf(m, __shfl_xor(m, off));
      if (ptg == 0) sred[chg * 8 + j] = m;
    }
    __syncthreads();
    if (tid < CT) out[(size_t)blockIdx.x * 1024 + cb + tid] = sred[tid];
  }
}

// ============ kgmax: g[c] = max over 512 point-block rows of gpart[512][1024]
__global__ __launch_bounds__(256) void kgmax(const float* __restrict__ gpart, float* __restrict__ g) {
  int t = blockIdx.x * 256 + threadIdx.x;  // 8192 threads: 1024 ch x 8 rowgroups
  int c = t & 1023, rg = t >> 10;
  const float* gp = gpart + (size_t)rg * 64 * 1024 + c;
  float m = 0.f;
#pragma unroll 8
  for (int r = 0; r < 64; ++r) m = fmaxf(m, gp[(size_t)r * 1024]);
  atomicMax((unsigned int*)(g + c), __float_as_uint(m));  // all values >= 0
}

// ============ kc5: c5[c] = W5[c][64:1088] @ g + b5[c]
__global__ __launch_bounds__(256) void kc5(
    const float* __restrict__ W5, const float* __restrict__ b5,
    const float* __restrict__ g, float* __restrict__ c5) {
  int tid = threadIdx.x;
  int ci = tid >> 3, kg = tid & 7;
  int c = blockIdx.x * 32 + ci;
  const float* wrow = W5 + (size_t)c * 1088 + 64 + kg * 128;
  const float* gp = g + kg * 128;
  float acc = 0.f;
#pragma unroll 8
  for (int k = 0; k < 128; ++k) acc += wrow[k] * gp[k];
#pragma unroll
  for (int off = 1; off <= 4; off <<= 1) acc += __shfl_xor(acc, off);
  if (kg == 0) c5[c] = acc + b5[c];
}

// ============ kL8: out[p] = z7[p] @ W8 + b8   K=128 split over 4 waves, 64 pts/block
__global__ __launch_bounds__(256) void kL8(
    const float* __restrict__ z7T, const float* __restrict__ W8, const float* __restrict__ b8,
    float* __restrict__ out) {
  __shared__ float part[4][64];
  int tid = threadIdx.x;
  int lane = tid & 63;
  int w = __builtin_amdgcn_readfirstlane(tid >> 6);
  int p = blockIdx.x * 64 + lane;
  float acc = 0.f;
#pragma unroll
  for (int j = 0; j < 32; ++j)
    acc = fmaf(z7T[(size_t)(w * 32 + j) * NPTS + p], W8[w * 32 + j], acc);
  part[w][lane] = acc;
  __syncthreads();
  if (tid < 64)
    out[blockIdx.x * 64 + tid] =
        part[0][tid] + part[1][tid] + part[2][tid] + part[3][tid] + b8[0];
}

extern "C" void kernel_launch(void* const* d_in, const int* in_sizes, int n_in,
                              void* d_out, int out_size, void* d_ws, size_t ws_size,
                              hipStream_t stream) {
  const float* x  = (const float*)d_in[0];
  const float* W1 = (const float*)d_in[1];  const float* b1 = (const float*)d_in[2];
  const float* W2 = (const float*)d_in[3];  const float* b2 = (const float*)d_in[4];
  const float* W3 = (const float*)d_in[5];  const float* b3 = (const float*)d_in[6];
  const float* W4 = (const float*)d_in[7];  const float* b4 = (const float*)d_in[8];
  const float* W5 = (const float*)d_in[9];  const float* b5 = (const float*)d_in[10];
  const float* W6 = (const float*)d_in[11]; const float* b6 = (const float*)d_in[12];
  const float* W7 = (const float*)d_in[13]; const float* b7 = (const float*)d_in[14];
  const float* W8 = (const float*)d_in[15]; const float* b8 = (const float*)d_in[16];
  float* out = (float*)d_out;

  // Workspace overlays (lifetimes):
  //   z5T  [0,128M)     L5->L6          z7T [0,32M)  L7->L8 (z5T dead)
  //   h2T  [128M,144M)  L2->L5
  //   h1T  [144M,160M)  k1a->L2
  //   y3T  [144M,176M)  L3->L4 (over dead h1T)
  //   gpart[176M,178M)  L4->kgmax
  //   z6T  [144M,208M)  L6->L7 (over dead y3T+gpart)
  //   g [208M,+4K)  c5 [208M+4K,+2K)
  char* ws = (char*)d_ws;
  float* z5T   = (float*)(ws);
  float* z7T   = (float*)(ws);
  float* h2T   = (float*)(ws + 134217728ULL);
  float* h1T   = (float*)(ws + 150994944ULL);
  float* y3T   = (float*)(ws + 150994944ULL);
  float* gpart = (float*)(ws + 184549376ULL);
  float* z6T   = (float*)(ws + 150994944ULL);
  float* g     = (float*)(ws + 218103808ULL);
  float* c5    = (float*)(ws + 218103808ULL + 4096);

  hipMemsetAsync(g, 0, 1024 * sizeof(float), stream);  // max identity (relu outputs >= 0)

  k1a<<<256, 256, 0, stream>>>(x, W1, b1, h1T);
  gemm2<256, 64, false><<<dim3(256, 1), 256, 0, stream>>>(h1T, W2, 64, 64, b2, h2T);     // L2
  gemm2<128, 128, false><<<dim3(512, 1), 256, 0, stream>>>(h2T, W3, 64, 64, b3, y3T);    // L3
  gemm2<128, 128, true><<<dim3(512, 8), 256, 0, stream>>>(y3T, W4, 128, 128, b4, gpart); // L4+max
  kgmax<<<32, 256, 0, stream>>>(gpart, g);
  kc5<<<16, 256, 0, stream>>>(W5, b5, g, c5);
  gemm2<128, 128, false><<<dim3(512, 4), 256, 0, stream>>>(h2T, W5, 1088, 64, c5, z5T);  // L5
  gemm2<128, 128, false><<<dim3(512, 2), 256, 0, stream>>>(z5T, W6, 512, 512, b6, z6T);  // L6
  gemm2<128, 128, false><<<dim3(512, 1), 256, 0, stream>>>(z6T, W7, 256, 256, b7, z7T);  // L7
  kL8<<<1024, 256, 0, stream>>>(z7T, W8, b8, out);
}

// Round 5
// 324.048 us; speedup vs baseline: 15.4487x; 2.0340x over previous
//
#include <hip/hip_runtime.h>

#define NPTS 65536

typedef __bf16 bf16_t;
typedef __bf16 bf16x8 __attribute__((ext_vector_type(8)));
typedef float f32x4 __attribute__((ext_vector_type(4)));

__device__ __forceinline__ float relu(float v) { return v > 0.f ? v : 0.f; }

// ============ kprep: split fp32 weights [N][K] (row stride `stride`) into bf16 hi/lo [N][K]
__global__ __launch_bounds__(256) void kprep(
    const float* __restrict__ src, int stride, int logK, int total,
    bf16_t* __restrict__ hi, bf16_t* __restrict__ lo) {
  int i = blockIdx.x * 256 + threadIdx.x;
  if (i >= total) return;
  int K = 1 << logK;
  int c = i >> logK, k = i & (K - 1);
  float v = src[(size_t)c * stride + k];
  bf16_t h = (bf16_t)v;
  hi[i] = h;
  lo[i] = (bf16_t)(v - (float)h);
}

// ============ k1a: h1[p][c] = relu(x @ W1.T + b1), split to bf16 hi/lo pairs
__global__ __launch_bounds__(256, 2) void k1a(
    const float* __restrict__ x, const float* __restrict__ W1, const float* __restrict__ b1,
    bf16_t* __restrict__ h1hi, bf16_t* __restrict__ h1lo) {
  int p = blockIdx.x * 256 + threadIdx.x;
  float x0 = x[p * 3 + 0], x1 = x[p * 3 + 1], x2 = x[p * 3 + 2];
  bf16x8 hv, lv;
#pragma unroll
  for (int j = 0; j < 8; ++j) {
#pragma unroll
    for (int i = 0; i < 8; ++i) {
      int c = j * 8 + i;
      float v = relu(fmaf(W1[c * 3], x0, fmaf(W1[c * 3 + 1], x1, fmaf(W1[c * 3 + 2], x2, b1[c]))));
      bf16_t h = (bf16_t)v;
      hv[i] = h;
      lv[i] = (bf16_t)(v - (float)h);
    }
    *(bf16x8*)(h1hi + (size_t)p * 64 + j * 8) = hv;
    *(bf16x8*)(h1lo + (size_t)p * 64 + j * 8) = lv;
  }
}

// ============ gemmM: C[p][n] = act(A[p][:]·W[n][:] + bias[n]) via 3-term split bf16 MFMA.
// A,W as hi/lo bf16 pairs, row-major k-contiguous. Tile 128 x TN, 4 waves (WM x WN),
// wave = (MI*16) x (NI*16) of 16x16x32 MFMAs.
// MODE 0: store relu+split pair.  MODE 1: fused column-max -> aux[bx*1024+c].
// MODE 2: fused final dot: out[p] = sum_n relu(C[p][n])*w8[n] + b8.
template <int TN, int WM, int WN, int MI, int NI, int MODE>
__global__ __launch_bounds__(256, 2) void gemmM(
    const bf16_t* __restrict__ Ahi, const bf16_t* __restrict__ Alo,
    const bf16_t* __restrict__ Whi, const bf16_t* __restrict__ Wlo,
    const float* __restrict__ bias, int K,
    bf16_t* __restrict__ Ohi, bf16_t* __restrict__ Olo,
    float* __restrict__ aux, const float* __restrict__ w8, const float* __restrict__ b8) {
  constexpr int KC = 32, KP = KC + 8;  // +8 halfwords: 5-superbank row stride, conflict-free b128
  __shared__ bf16_t sAh[128][KP], sAl[128][KP];
  __shared__ bf16_t sBh[TN][KP], sBl[TN][KP];
  __shared__ float sredM[2][TN];
  __shared__ float spart[2][128];

  int tid = threadIdx.x;
  int lane = tid & 63;
  int w = tid >> 6;
  int wm = w % WM, wn = w / WM;
  int lane15 = lane & 15, quad = lane >> 4;
  int m_w = wm * MI * 16, n_w = wn * NI * 16;
  int p0 = blockIdx.x * 128;
  int cb = blockIdx.y * TN;

  f32x4 acc[MI][NI];
#pragma unroll
  for (int ni = 0; ni < NI; ++ni) {
    float bv = bias[cb + n_w + ni * 16 + lane15];
#pragma unroll
    for (int mi = 0; mi < MI; ++mi) acc[mi][ni] = (f32x4){bv, bv, bv, bv};
  }

  for (int kc0 = 0; kc0 < K; kc0 += KC) {
    if (kc0) __syncthreads();
    // stage A chunk: 128 rows x 32 k, 16B per thread-iter
#pragma unroll
    for (int it = 0; it < 2; ++it) {
      int c = tid + it * 256;
      int row = c >> 2, kq = (c & 3) * 8;
      size_t ga = (size_t)(p0 + row) * K + kc0 + kq;
      *(bf16x8*)&sAh[row][kq] = *(const bf16x8*)(Ahi + ga);
      *(bf16x8*)&sAl[row][kq] = *(const bf16x8*)(Alo + ga);
    }
    // stage W chunk: TN rows x 32 k
#pragma unroll
    for (int it = 0; it < TN / 64; ++it) {
      int c = tid + it * 256;
      int row = c >> 2, kq = (c & 3) * 8;
      size_t ga = (size_t)(cb + row) * K + kc0 + kq;
      *(bf16x8*)&sBh[row][kq] = *(const bf16x8*)(Whi + ga);
      *(bf16x8*)&sBl[row][kq] = *(const bf16x8*)(Wlo + ga);
    }
    __syncthreads();

    bf16x8 ah[MI], al[MI], bh[NI], bl[NI];
#pragma unroll
    for (int mi = 0; mi < MI; ++mi) {
      ah[mi] = *(const bf16x8*)&sAh[m_w + mi * 16 + lane15][quad * 8];
      al[mi] = *(const bf16x8*)&sAl[m_w + mi * 16 + lane15][quad * 8];
    }
#pragma unroll
    for (int ni = 0; ni < NI; ++ni) {
      bh[ni] = *(const bf16x8*)&sBh[n_w + ni * 16 + lane15][quad * 8];
      bl[ni] = *(const bf16x8*)&sBl[n_w + ni * 16 + lane15][quad * 8];
    }
#pragma unroll
    for (int mi = 0; mi < MI; ++mi)
#pragma unroll
      for (int ni = 0; ni < NI; ++ni) {
        acc[mi][ni] = __builtin_amdgcn_mfma_f32_16x16x32_bf16(ah[mi], bh[ni], acc[mi][ni], 0, 0, 0);
        acc[mi][ni] = __builtin_amdgcn_mfma_f32_16x16x32_bf16(al[mi], bh[ni], acc[mi][ni], 0, 0, 0);
        acc[mi][ni] = __builtin_amdgcn_mfma_f32_16x16x32_bf16(ah[mi], bl[ni], acc[mi][ni], 0, 0, 0);
      }
  }

  if (MODE == 0) {
    int N = gridDim.y * TN;
#pragma unroll
    for (int mi = 0; mi < MI; ++mi)
#pragma unroll
      for (int ni = 0; ni < NI; ++ni) {
        int c = cb + n_w + ni * 16 + lane15;
#pragma unroll
        for (int reg = 0; reg < 4; ++reg) {
          int p = p0 + m_w + mi * 16 + quad * 4 + reg;
          float v = relu(acc[mi][ni][reg]);
          bf16_t h = (bf16_t)v;
          Ohi[(size_t)p * N + c] = h;
          Olo[(size_t)p * N + c] = (bf16_t)(v - (float)h);
        }
      }
  } else if (MODE == 1) {
    // fused max over this block's 128 points
    float mx[NI];
#pragma unroll
    for (int ni = 0; ni < NI; ++ni) {
      float m = 0.f;
#pragma unroll
      for (int mi = 0; mi < MI; ++mi)
#pragma unroll
        for (int reg = 0; reg < 4; ++reg) m = fmaxf(m, relu(acc[mi][ni][reg]));
      m = fmaxf(m, __shfl_xor(m, 16));
      m = fmaxf(m, __shfl_xor(m, 32));
      mx[ni] = m;
    }
    if (lane < 16) {
#pragma unroll
      for (int ni = 0; ni < NI; ++ni) sredM[wm][n_w + ni * 16 + lane] = mx[ni];
    }
    __syncthreads();
    if (tid < TN)
      aux[(size_t)blockIdx.x * 1024 + cb + tid] = fmaxf(sredM[0][tid], sredM[1][tid]);
  } else {
    // fused final dot with w8 (cb == 0, TN == full N == 128)
    float w8v[NI];
#pragma unroll
    for (int ni = 0; ni < NI; ++ni) w8v[ni] = w8[n_w + ni * 16 + lane15];
#pragma unroll
    for (int mi = 0; mi < MI; ++mi)
#pragma unroll
      for (int reg = 0; reg < 4; ++reg) {
        float s = 0.f;
#pragma unroll
        for (int ni = 0; ni < NI; ++ni) s = fmaf(relu(acc[mi][ni][reg]), w8v[ni], s);
        s += __shfl_xor(s, 1);
        s += __shfl_xor(s, 2);
        s += __shfl_xor(s, 4);
        s += __shfl_xor(s, 8);
        if (lane15 == 0) spart[wn][m_w + mi * 16 + quad * 4 + reg] = s;
      }
    __syncthreads();
    if (tid < 128) aux[p0 + tid] = spart[0][tid] + spart[1][tid] + b8[0];
  }
}

// ============ kgmax: g[c] = max over 512 point-block rows of gpart[512][1024]
__global__ __launch_bounds__(256) void kgmax(const float* __restrict__ gpart, float* __restrict__ g) {
  int t = blockIdx.x * 256 + threadIdx.x;  // 8192 threads: 1024 ch x 8 rowgroups
  int c = t & 1023, rg = t >> 10;
  const float* gp = gpart + (size_t)rg * 64 * 1024 + c;
  float m = 0.f;
#pragma unroll 8
  for (int r = 0; r < 64; ++r) m = fmaxf(m, gp[(size_t)r * 1024]);
  atomicMax((unsigned int*)(g + c), __float_as_uint(m));  // all values >= 0
}

// ============ kc5: c5[c] = W5[c][64:1088] @ g + b5[c]   (full fp32 path)
__global__ __launch_bounds__(256) void kc5(
    const float* __restrict__ W5, const float* __restrict__ b5,
    const float* __restrict__ g, float* __restrict__ c5) {
  int tid = threadIdx.x;
  int ci = tid >> 3, kg = tid & 7;
  int c = blockIdx.x * 32 + ci;
  const float* wrow = W5 + (size_t)c * 1088 + 64 + kg * 128;
  const float* gp = g + kg * 128;
  float acc = 0.f;
#pragma unroll 8
  for (int k = 0; k < 128; ++k) acc += wrow[k] * gp[k];
#pragma unroll
  for (int off = 1; off <= 4; off <<= 1) acc += __shfl_xor(acc, off);
  if (kg == 0) c5[c] = acc + b5[c];
}

extern "C" void kernel_launch(void* const* d_in, const int* in_sizes, int n_in,
                              void* d_out, int out_size, void* d_ws, size_t ws_size,
                              hipStream_t stream) {
  const float* x  = (const float*)d_in[0];
  const float* W1 = (const float*)d_in[1];  const float* b1 = (const float*)d_in[2];
  const float* W2 = (const float*)d_in[3];  const float* b2 = (const float*)d_in[4];
  const float* W3 = (const float*)d_in[5];  const float* b3 = (const float*)d_in[6];
  const float* W4 = (const float*)d_in[7];  const float* b4 = (const float*)d_in[8];
  const float* W5 = (const float*)d_in[9];  const float* b5 = (const float*)d_in[10];
  const float* W6 = (const float*)d_in[11]; const float* b6 = (const float*)d_in[12];
  const float* W7 = (const float*)d_in[13]; const float* b7 = (const float*)d_in[14];
  const float* W8 = (const float*)d_in[15]; const float* b8 = (const float*)d_in[16];
  float* out = (float*)d_out;

  // Workspace overlays (MB offsets; lifetimes):
  //   y3 pair  [0,32)     L3->L4     (then overwritten by z5 at L5)
  //   z5 pair  [0,128)    L5->L6
  //   h2 pair  [128,144)  L2->L5
  //   h1 pair  [144,160)  k1a->L2    (then overwritten by z6 at L6)
  //   z6 pair  [144,208)  L6->L7
  //   gpart [208,210), g/c5/weight-pairs [210,~212)
  const size_t MB = 1ull << 20;
  char* ws = (char*)d_ws;
  bf16_t* y3h = (bf16_t*)(ws);
  bf16_t* y3l = (bf16_t*)(ws + 16 * MB);
  bf16_t* z5h = (bf16_t*)(ws);
  bf16_t* z5l = (bf16_t*)(ws + 64 * MB);
  bf16_t* h2h = (bf16_t*)(ws + 128 * MB);
  bf16_t* h2l = (bf16_t*)(ws + 136 * MB);
  bf16_t* h1h = (bf16_t*)(ws + 144 * MB);
  bf16_t* h1l = (bf16_t*)(ws + 152 * MB);
  bf16_t* z6h = (bf16_t*)(ws + 144 * MB);
  bf16_t* z6l = (bf16_t*)(ws + 176 * MB);
  float* gpart = (float*)(ws + 208 * MB);
  float* g     = (float*)(ws + 210 * MB);
  float* c5    = (float*)(ws + 210 * MB + 4096);
  char* wb = ws + 210 * MB + 65536;
  bf16_t* W2h = (bf16_t*)(wb);            bf16_t* W2l = (bf16_t*)(wb + 8192);
  bf16_t* W3h = (bf16_t*)(wb + 16384);    bf16_t* W3l = (bf16_t*)(wb + 32768);
  bf16_t* W4h = (bf16_t*)(wb + 65536);    bf16_t* W4l = (bf16_t*)(wb + 65536 + 262144);
  bf16_t* W5h = (bf16_t*)(wb + 655360);   bf16_t* W5l = (bf16_t*)(wb + 655360 + 65536);
  bf16_t* W6h = (bf16_t*)(wb + 851968);   bf16_t* W6l = (bf16_t*)(wb + 851968 + 262144);
  bf16_t* W7h = (bf16_t*)(wb + 1441792);  bf16_t* W7l = (bf16_t*)(wb + 1441792 + 65536);

  hipMemsetAsync(g, 0, 1024 * sizeof(float), stream);  // max identity (relu outputs >= 0)

  kprep<<<16, 256, 0, stream>>>(W2, 64, 6, 64 * 64, W2h, W2l);
  kprep<<<32, 256, 0, stream>>>(W3, 64, 6, 128 * 64, W3h, W3l);
  kprep<<<512, 256, 0, stream>>>(W4, 128, 7, 1024 * 128, W4h, W4l);
  kprep<<<128, 256, 0, stream>>>(W5, 1088, 6, 512 * 64, W5h, W5l);  // W5[:, :64]
  kprep<<<512, 256, 0, stream>>>(W6, 512, 9, 256 * 512, W6h, W6l);
  kprep<<<128, 256, 0, stream>>>(W7, 256, 8, 128 * 256, W7h, W7l);

  k1a<<<256, 256, 0, stream>>>(x, W1, b1, h1h, h1l);
  gemmM<64, 4, 1, 2, 4, 0><<<dim3(512, 1), 256, 0, stream>>>(
      h1h, h1l, W2h, W2l, b2, 64, h2h, h2l, nullptr, nullptr, nullptr);        // L2
  gemmM<128, 2, 2, 4, 4, 0><<<dim3(512, 1), 256, 0, stream>>>(
      h2h, h2l, W3h, W3l, b3, 64, y3h, y3l, nullptr, nullptr, nullptr);        // L3
  gemmM<128, 2, 2, 4, 4, 1><<<dim3(512, 8), 256, 0, stream>>>(
      y3h, y3l, W4h, W4l, b4, 128, nullptr, nullptr, gpart, nullptr, nullptr); // L4 + max
  kgmax<<<32, 256, 0, stream>>>(gpart, g);
  kc5<<<16, 256, 0, stream>>>(W5, b5, g, c5);
  gemmM<128, 2, 2, 4, 4, 0><<<dim3(512, 4), 256, 0, stream>>>(
      h2h, h2l, W5h, W5l, c5, 64, z5h, z5l, nullptr, nullptr, nullptr);        // L5
  gemmM<128, 2, 2, 4, 4, 0><<<dim3(512, 2), 256, 0, stream>>>(
      z5h, z5l, W6h, W6l, b6, 512, z6h, z6l, nullptr, nullptr, nullptr);       // L6
  gemmM<128, 2, 2, 4, 4, 2><<<dim3(512, 1), 256, 0, stream>>>(
      z6h, z6l, W7h, W7l, b7, 256, nullptr, nullptr, out, W8, b8);             // L7 + L8
}